// Round 16
// baseline (131.798 us; speedup 1.0000x reference)
//
#include <hip/hip_runtime.h>

// Geometry (fixed): imgs [2,1,128,128,128] f32, flow [2,3,128,128,128] f32
#define VOL   4194304
#define FLOWN 12582912
#define SMCNT 12484608.0f   // 2*3*127*128*128
#define WIN_INV (1.0f / 729.0f)

__device__ __forceinline__ void block_reduce_atomic(float v, float* red, float* dst) {
#pragma unroll
    for (int off = 32; off; off >>= 1) v += __shfl_down(v, off);
    if ((threadIdx.x & 63) == 0) red[threadIdx.x >> 6] = v;
    __syncthreads();
    if (threadIdx.x == 0) atomicAdd(dst, red[0] + red[1] + red[2] + red[3]);
}

struct __align__(16) NccLds {
    float wst[2][5][16][25];  // [plane][chan][w][rr]; rr 24->25 (+1 pad).
    float hst[2][5][16][16];  // [plane][chan][w][h]; final read 2-way = free
};
// 16000 + 10240 = 26240 B -> 6 blocks/CU

// sliding 9-window over 12 inputs -> 4 outputs, transposed write at row wrr
#define WSLIDE(c, X0,X1,X2,X3,X4,X5,X6,X7,X8,X9,X10,X11)                   \
    {                                                                      \
        const float o0 = X0+X1+X2+X3+X4+X5+X6+X7+X8;                       \
        const float o1 = o0 - X0 + X9;                                     \
        const float o2 = o1 - X1 + X10;                                    \
        const float o3 = o2 - X2 + X11;                                    \
        L->wst[wpl][c][wq4 + 0][wrr] = o0;                                 \
        L->wst[wpl][c][wq4 + 1][wrr] = o1;                                 \
        L->wst[wpl][c][wq4 + 2][wrr] = o2;                                 \
        L->wst[wpl][c][wq4 + 3][wrr] = o3;                                 \
    }

#define EMIT {                                                             \
        const float cross = S[4] - S[0] * S[1] * WIN_INV;                  \
        const float iv    = S[2] - S[0] * S[0] * WIN_INV;                  \
        const float jv    = S[3] - S[1] * S[1] * WIN_INV;                  \
        local += cross * cross / (iv * jv + 1e-5f);                       \
    }

// Block = (n, 16h x 16w tile, 32-deep d-chunk): 40 planes in 20 pairs, rolled
// loop, 512 blocks. R16: these blocks are dispatched LAST -- they run their
// serial 20-pair chains on a CLEAN machine after the streaming blocks drain
// (the R11-R13 profile showed the chain stretched ~3x by issue-slot sharing
// with dense-VMEM streaming waves; setprio was null against it).
__device__ void ncc_block(const float* __restrict__ I, const float* __restrict__ J,
                          float* __restrict__ acc, NccLds* L, float* red, int nb) {
    const int wt = nb & 7, ht = (nb >> 3) & 7, dc = (nb >> 6) & 3, n = nb >> 8;
    const int w0 = wt << 4, h0 = ht << 4, d0 = dc << 5;
    const int tid = threadIdx.x;
    const int th = tid & 15;        // owned h
    const int tw = tid >> 4;        // owned w

    // W-phase decomposition: threads 0..191 -> (plane 0/1, rr 0..23, q 0..3)
    const int wpl = tid / 96;
    const int wit = tid - wpl * 96;
    const int wrr = wit >> 2;
    const int wq4 = (wit & 3) << 2;
    const int gh  = h0 - 4 + wrr;
    const int gwb = w0 + wq4 - 4;   // first of 3 aligned float4 columns
    const bool wthr = (tid < 192) && ((unsigned)gh < 128u);

    float hist[5][9];
#pragma unroll
    for (int c = 0; c < 5; ++c)
#pragma unroll
        for (int k = 0; k < 9; ++k) hist[c][k] = 0.f;
    float S[5] = {0.f, 0.f, 0.f, 0.f, 0.f};
    float local = 0.f;
    const long nbase = (long)n * 2097152;

    float4 Pi0, Pi1, Pi2, Pj0, Pj1, Pj2;   // prefetched regs for pair pp

    auto issue_loads = [&](int pp) {
        const int dp = d0 - 4 + 2 * pp + wpl;
        const float4 z4 = make_float4(0.f, 0.f, 0.f, 0.f);
        Pi0 = Pi1 = Pi2 = Pj0 = Pj1 = Pj2 = z4;
        if (wthr && (unsigned)dp < 128u) {
            const float* Ip = I + nbase + (long)dp * 16384 + gh * 128 + gwb;
            const float* Jp = J + nbase + (long)dp * 16384 + gh * 128 + gwb;
            if (gwb >= 0)   { Pi0 = *(const float4*)Ip;       Pj0 = *(const float4*)Jp; }
            Pi1 = *(const float4*)(Ip + 4);                   Pj1 = *(const float4*)(Jp + 4);
            if (gwb <= 116) { Pi2 = *(const float4*)(Ip + 8); Pj2 = *(const float4*)(Jp + 8); }
        }
    };

    __builtin_amdgcn_s_setprio(1);          // ncc waves own the critical path
    issue_loads(0);
#pragma unroll 1
    for (int pp = 0; pp < 20; ++pp) {
        // ---- W phase: prefetched regs -> wst (transposed) ----
        {
            const int dp = d0 - 4 + 2 * pp + wpl;
            if (tid < 192 && (unsigned)dp < 128u) {
                const float4 i0 = Pi0, i1 = Pi1, i2 = Pi2;
                const float4 j0 = Pj0, j1 = Pj1, j2 = Pj2;
                WSLIDE(0, i0.x,i0.y,i0.z,i0.w, i1.x,i1.y,i1.z,i1.w, i2.x,i2.y,i2.z,i2.w)
                WSLIDE(1, j0.x,j0.y,j0.z,j0.w, j1.x,j1.y,j1.z,j1.w, j2.x,j2.y,j2.z,j2.w)
                WSLIDE(2, i0.x*i0.x,i0.y*i0.y,i0.z*i0.z,i0.w*i0.w,
                          i1.x*i1.x,i1.y*i1.y,i1.z*i1.z,i1.w*i1.w,
                          i2.x*i2.x,i2.y*i2.y,i2.z*i2.z,i2.w*i2.w)
                WSLIDE(3, j0.x*j0.x,j0.y*j0.y,j0.z*j0.z,j0.w*j0.w,
                          j1.x*j1.x,j1.y*j1.y,j1.z*j1.z,j1.w*j1.w,
                          j2.x*j2.x,j2.y*j2.y,j2.z*j2.z,j2.w*j2.w)
                WSLIDE(4, i0.x*j0.x,i0.y*j0.y,i0.z*j0.z,i0.w*j0.w,
                          i1.x*j1.x,i1.y*j1.y,i1.z*j1.z,i1.w*j1.w,
                          i2.x*j2.x,i2.y*j2.y,i2.z*j2.z,i2.w*j2.w)
            }
        }
        // issue next pair's loads now; they complete during H + final + barriers
        if (pp < 19) issue_loads(pp + 1);
        __syncthreads();
        // ---- H phase: 640 items = (plane, c, w, qh); sliding along rr ----
#pragma unroll
        for (int rep = 0; rep < 3; ++rep) {
            int id = -1;
            if (rep < 2) id = tid + rep * 256;
            else if (tid >= 128) id = 384 + tid;      // waves 2,3 take the tail
            if (id >= 0 && id < 640) {
                const int pl = id >= 320;
                const int r2 = id - pl * 320;
                const int c  = r2 >> 6;
                const int w  = (r2 >> 2) & 15;
                const int qh = r2 & 3;
                const int dp = d0 - 4 + 2 * pp + pl;
                if ((unsigned)dp < 128u) {
                    const float* sp = &L->wst[pl][c][w][qh << 2];
                    const float4 a0 = *(const float4*)sp;
                    const float4 a1 = *(const float4*)(sp + 4);
                    const float4 a2 = *(const float4*)(sp + 8);
                    const float o0 = a0.x+a0.y+a0.z+a0.w+a1.x+a1.y+a1.z+a1.w+a2.x;
                    const float o1 = o0 - a0.x + a2.y;
                    const float o2 = o1 - a0.y + a2.z;
                    const float o3 = o2 - a0.z + a2.w;
                    *(float4*)&L->hst[pl][c][w][qh << 2] = make_float4(o0, o1, o2, o3);
                }
            }
        }
        __syncthreads();
        // ---- final: D running window for both planes (shift ring) ----
        {
            const int dp0 = d0 - 4 + 2 * pp;
            float p0[5], p1[5];
            if ((unsigned)dp0 < 128u) {
#pragma unroll
                for (int c = 0; c < 5; ++c) p0[c] = L->hst[0][c][tw][th];
            } else {
#pragma unroll
                for (int c = 0; c < 5; ++c) p0[c] = 0.f;
            }
            if ((unsigned)(dp0 + 1) < 128u) {
#pragma unroll
                for (int c = 0; c < 5; ++c) p1[c] = L->hst[1][c][tw][th];
            } else {
#pragma unroll
                for (int c = 0; c < 5; ++c) p1[c] = 0.f;
            }
#pragma unroll
            for (int c = 0; c < 5; ++c) S[c] += p0[c] - hist[c][8];
            if (pp >= 4) EMIT
#pragma unroll
            for (int c = 0; c < 5; ++c) S[c] += p1[c] - hist[c][7];
            if (pp >= 4) EMIT
#pragma unroll
            for (int c = 0; c < 5; ++c) {
                hist[c][8] = hist[c][6]; hist[c][7] = hist[c][5];
                hist[c][6] = hist[c][4]; hist[c][5] = hist[c][3];
                hist[c][4] = hist[c][2]; hist[c][3] = hist[c][1];
                hist[c][2] = hist[c][0];
                hist[c][1] = p0[c];
                hist[c][0] = p1[c];
            }
        }
    }
    __builtin_amdgcn_s_setprio(0);
    block_reduce_atomic(local, red, &acc[0]);
}

__device__ void mse_block(const float4* __restrict__ a, const float4* __restrict__ b,
                          float* __restrict__ acc, float* red, int mb) {
    float local = 0.f;
    for (int i = mb * 256 + threadIdx.x; i < VOL / 4; i += 512 * 256) {
        const float4 x = a[i], y = b[i];
        const float d0 = x.x - y.x, d1 = x.y - y.y, d2 = x.z - y.z, d3 = x.w - y.w;
        local += d0 * d0 + d1 * d1 + d2 * d2 + d3 * d3;
    }
    block_reduce_atomic(local, red, &acc[1]);
}

__device__ void smooth_block(const float4* __restrict__ s,
                             float* __restrict__ acc, float* red, int sb) {
    float local = 0.f;
    for (int f = sb * 256 + threadIdx.x; f < FLOWN / 4; f += 2048 * 256) {
        const int w4 = f & 31, h = (f >> 5) & 127, d = (f >> 12) & 127;
        const float4 v = s[f];
        const float t1 = v.y - v.x, t2 = v.z - v.y, t3 = v.w - v.z;
        local += t1 * t1 + t2 * t2 + t3 * t3;
        if (w4 < 31) {
            const float nx = ((const float*)s)[4 * f + 4];
            const float t = nx - v.w;
            local += t * t;
        }
        if (h < 127) {
            const float4 nh = s[f + 32];
            const float u0 = nh.x - v.x, u1 = nh.y - v.y, u2 = nh.z - v.z, u3 = nh.w - v.w;
            local += u0 * u0 + u1 * u1 + u2 * u2 + u3 * u3;
        }
        if (d < 127) {
            const float4 nd = s[f + 4096];
            const float u0 = nd.x - v.x, u1 = nd.y - v.y, u2 = nd.z - v.z, u3 = nd.w - v.w;
            local += u0 * u0 + u1 * u1 + u2 * u2 + u3 * u3;
        }
    }
    block_reduce_atomic(local, red, &acc[2]);
}

// R16 schedule inversion: streaming blocks (2560) dispatch FIRST and drain
// HBM at full residency (24 waves/CU); the 512 ncc blocks dispatch LAST and
// run their serial 20-pair chains on a contention-free machine.
__global__ __launch_bounds__(256) void fused_k(const float* __restrict__ imgsA,
                                               const float* __restrict__ recon,
                                               const float* __restrict__ warped,
                                               const float* __restrict__ flow,
                                               float* __restrict__ acc) {
    __shared__ NccLds Lsh;
    __shared__ float red[4];
    const int g = blockIdx.x;
    if (g >= 2560) {
        ncc_block(warped, imgsA, acc, &Lsh, red, g - 2560);
    } else {
        const int q = g / 5, r = g - q * 5;
        if (r == 0) mse_block((const float4*)imgsA, (const float4*)recon, acc, red, q);
        else        smooth_block((const float4*)flow, acc, red, q * 4 + (r - 1));
    }
}

__global__ void fin_k(const float* __restrict__ acc, float* __restrict__ out) {
    if (threadIdx.x == 0) {
        out[0] = 1.0f - acc[0] * (1.0f / (float)VOL);
        out[1] = acc[1] * (1.0f / (float)VOL);
        out[2] = acc[2] * (1.0f / (3.0f * SMCNT));
    }
}

extern "C" void kernel_launch(void* const* d_in, const int* in_sizes, int n_in,
                              void* d_out, int out_size, void* d_ws, size_t ws_size,
                              hipStream_t stream) {
    const float* imgsA  = (const float*)d_in[0];
    const float* recon  = (const float*)d_in[1];
    const float* warped = (const float*)d_in[2];
    const float* flow   = (const float*)d_in[3];
    float* out = (float*)d_out;
    float* acc = (float*)d_ws;

    hipMemsetAsync(d_ws, 0, 16, stream);
    fused_k<<<3072, 256, 0, stream>>>(imgsA, recon, warped, flow, acc);
    fin_k<<<1, 64, 0, stream>>>(acc, out);
}

// Round 17
// 69.269 us; speedup vs baseline: 1.9027x; 1.9027x over previous
//
#include <hip/hip_runtime.h>

// Geometry (fixed): imgs [2,1,128,128,128] f32, flow [2,3,128,128,128] f32
#define VOL   4194304
#define FLOWN 12582912
#define SMCNT 12484608.0f   // 2*3*127*128*128
#define WIN_INV (1.0f / 729.0f)

__device__ __forceinline__ void block_reduce_atomic(float v, float* red, float* dst) {
#pragma unroll
    for (int off = 32; off; off >>= 1) v += __shfl_down(v, off);
    if ((threadIdx.x & 63) == 0) red[threadIdx.x >> 6] = v;
    __syncthreads();
    if (threadIdx.x == 0) atomicAdd(dst, red[0] + red[1] + red[2] + red[3]);
}

// Counted barrier (HK pattern): order LDS (lgkmcnt) but let prefetched
// global loads stay IN FLIGHT across the barrier. __syncthreads() would
// emit s_waitcnt vmcnt(0) -> force-drains the next pair's prefetch at full
// HBM/L2 latency EVERY pair (the ~2x chain stretch seen in R11-R16).
__device__ __forceinline__ void lds_barrier() {
    asm volatile("s_waitcnt lgkmcnt(0)" ::: "memory");
    __builtin_amdgcn_s_barrier();
}

struct __align__(16) NccLds {
    float wst[2][5][16][25];  // [plane][chan][w][rr]; rr 24->25 (+1 pad).
    float hst[2][5][16][16];  // [plane][chan][w][h]; final read 2-way = free
};
// 16000 + 10240 = 26240 B -> 6 blocks/CU

// sliding 9-window over 12 inputs -> 4 outputs, transposed write at row wrr
#define WSLIDE(c, X0,X1,X2,X3,X4,X5,X6,X7,X8,X9,X10,X11)                   \
    {                                                                      \
        const float o0 = X0+X1+X2+X3+X4+X5+X6+X7+X8;                       \
        const float o1 = o0 - X0 + X9;                                     \
        const float o2 = o1 - X1 + X10;                                    \
        const float o3 = o2 - X2 + X11;                                    \
        L->wst[wpl][c][wq4 + 0][wrr] = o0;                                 \
        L->wst[wpl][c][wq4 + 1][wrr] = o1;                                 \
        L->wst[wpl][c][wq4 + 2][wrr] = o2;                                 \
        L->wst[wpl][c][wq4 + 3][wrr] = o3;                                 \
    }

#define EMIT {                                                             \
        const float cross = S[4] - S[0] * S[1] * WIN_INV;                  \
        const float iv    = S[2] - S[0] * S[0] * WIN_INV;                  \
        const float jv    = S[3] - S[1] * S[1] * WIN_INV;                  \
        local += cross * cross / (iv * jv + 1e-5f);                       \
    }

// Block = (n, 16h x 16w tile, 32-deep d-chunk): 40 planes in 20 pairs,
// rolled loop, 512 blocks (2/CU) + 4 streaming slots/CU. Identical to R13
// except the two in-loop barriers are lgkmcnt-only (prefetch survives).
__device__ void ncc_block(const float* __restrict__ I, const float* __restrict__ J,
                          float* __restrict__ acc, NccLds* L, float* red, int nb) {
    const int wt = nb & 7, ht = (nb >> 3) & 7, dc = (nb >> 6) & 3, n = nb >> 8;
    const int w0 = wt << 4, h0 = ht << 4, d0 = dc << 5;
    const int tid = threadIdx.x;
    const int th = tid & 15;        // owned h
    const int tw = tid >> 4;        // owned w

    // W-phase decomposition: threads 0..191 -> (plane 0/1, rr 0..23, q 0..3)
    const int wpl = tid / 96;
    const int wit = tid - wpl * 96;
    const int wrr = wit >> 2;
    const int wq4 = (wit & 3) << 2;
    const int gh  = h0 - 4 + wrr;
    const int gwb = w0 + wq4 - 4;   // first of 3 aligned float4 columns
    const bool wthr = (tid < 192) && ((unsigned)gh < 128u);

    float hist[5][9];
#pragma unroll
    for (int c = 0; c < 5; ++c)
#pragma unroll
        for (int k = 0; k < 9; ++k) hist[c][k] = 0.f;
    float S[5] = {0.f, 0.f, 0.f, 0.f, 0.f};
    float local = 0.f;
    const long nbase = (long)n * 2097152;

    float4 Pi0, Pi1, Pi2, Pj0, Pj1, Pj2;   // prefetched regs for pair pp

    auto issue_loads = [&](int pp) {
        const int dp = d0 - 4 + 2 * pp + wpl;
        const float4 z4 = make_float4(0.f, 0.f, 0.f, 0.f);
        Pi0 = Pi1 = Pi2 = Pj0 = Pj1 = Pj2 = z4;
        if (wthr && (unsigned)dp < 128u) {
            const float* Ip = I + nbase + (long)dp * 16384 + gh * 128 + gwb;
            const float* Jp = J + nbase + (long)dp * 16384 + gh * 128 + gwb;
            if (gwb >= 0)   { Pi0 = *(const float4*)Ip;       Pj0 = *(const float4*)Jp; }
            Pi1 = *(const float4*)(Ip + 4);                   Pj1 = *(const float4*)(Jp + 4);
            if (gwb <= 116) { Pi2 = *(const float4*)(Ip + 8); Pj2 = *(const float4*)(Jp + 8); }
        }
    };

    __builtin_amdgcn_s_setprio(1);
    issue_loads(0);
#pragma unroll 1
    for (int pp = 0; pp < 20; ++pp) {
        // ---- W phase: prefetched regs -> wst (transposed) ----
        {
            const int dp = d0 - 4 + 2 * pp + wpl;
            if (tid < 192 && (unsigned)dp < 128u) {
                const float4 i0 = Pi0, i1 = Pi1, i2 = Pi2;
                const float4 j0 = Pj0, j1 = Pj1, j2 = Pj2;
                WSLIDE(0, i0.x,i0.y,i0.z,i0.w, i1.x,i1.y,i1.z,i1.w, i2.x,i2.y,i2.z,i2.w)
                WSLIDE(1, j0.x,j0.y,j0.z,j0.w, j1.x,j1.y,j1.z,j1.w, j2.x,j2.y,j2.z,j2.w)
                WSLIDE(2, i0.x*i0.x,i0.y*i0.y,i0.z*i0.z,i0.w*i0.w,
                          i1.x*i1.x,i1.y*i1.y,i1.z*i1.z,i1.w*i1.w,
                          i2.x*i2.x,i2.y*i2.y,i2.z*i2.z,i2.w*i2.w)
                WSLIDE(3, j0.x*j0.x,j0.y*j0.y,j0.z*j0.z,j0.w*j0.w,
                          j1.x*j1.x,j1.y*j1.y,j1.z*j1.z,j1.w*j1.w,
                          j2.x*j2.x,j2.y*j2.y,j2.z*j2.z,j2.w*j2.w)
                WSLIDE(4, i0.x*j0.x,i0.y*j0.y,i0.z*j0.z,i0.w*j0.w,
                          i1.x*j1.x,i1.y*j1.y,i1.z*j1.z,i1.w*j1.w,
                          i2.x*j2.x,i2.y*j2.y,i2.z*j2.z,i2.w*j2.w)
            }
        }
        // issue next pair's loads; they stay in flight ACROSS the barriers
        // and are waited on only at next pair's W phase (vmcnt at use).
        if (pp < 19) issue_loads(pp + 1);
        lds_barrier();
        // ---- H phase: 640 items = (plane, c, w, qh); sliding along rr ----
#pragma unroll
        for (int rep = 0; rep < 3; ++rep) {
            int id = -1;
            if (rep < 2) id = tid + rep * 256;
            else if (tid >= 128) id = 384 + tid;      // waves 2,3 take the tail
            if (id >= 0 && id < 640) {
                const int pl = id >= 320;
                const int r2 = id - pl * 320;
                const int c  = r2 >> 6;
                const int w  = (r2 >> 2) & 15;
                const int qh = r2 & 3;
                const int dp = d0 - 4 + 2 * pp + pl;
                if ((unsigned)dp < 128u) {
                    const float* sp = &L->wst[pl][c][w][qh << 2];
                    const float4 a0 = *(const float4*)sp;
                    const float4 a1 = *(const float4*)(sp + 4);
                    const float4 a2 = *(const float4*)(sp + 8);
                    const float o0 = a0.x+a0.y+a0.z+a0.w+a1.x+a1.y+a1.z+a1.w+a2.x;
                    const float o1 = o0 - a0.x + a2.y;
                    const float o2 = o1 - a0.y + a2.z;
                    const float o3 = o2 - a0.z + a2.w;
                    *(float4*)&L->hst[pl][c][w][qh << 2] = make_float4(o0, o1, o2, o3);
                }
            }
        }
        lds_barrier();
        // ---- final: D running window for both planes (shift ring) ----
        {
            const int dp0 = d0 - 4 + 2 * pp;
            float p0[5], p1[5];
            if ((unsigned)dp0 < 128u) {
#pragma unroll
                for (int c = 0; c < 5; ++c) p0[c] = L->hst[0][c][tw][th];
            } else {
#pragma unroll
                for (int c = 0; c < 5; ++c) p0[c] = 0.f;
            }
            if ((unsigned)(dp0 + 1) < 128u) {
#pragma unroll
                for (int c = 0; c < 5; ++c) p1[c] = L->hst[1][c][tw][th];
            } else {
#pragma unroll
                for (int c = 0; c < 5; ++c) p1[c] = 0.f;
            }
#pragma unroll
            for (int c = 0; c < 5; ++c) S[c] += p0[c] - hist[c][8];
            if (pp >= 4) EMIT
#pragma unroll
            for (int c = 0; c < 5; ++c) S[c] += p1[c] - hist[c][7];
            if (pp >= 4) EMIT
#pragma unroll
            for (int c = 0; c < 5; ++c) {
                hist[c][8] = hist[c][6]; hist[c][7] = hist[c][5];
                hist[c][6] = hist[c][4]; hist[c][5] = hist[c][3];
                hist[c][4] = hist[c][2]; hist[c][3] = hist[c][1];
                hist[c][2] = hist[c][0];
                hist[c][1] = p0[c];
                hist[c][0] = p1[c];
            }
        }
        // NOTE: no barrier here; hst for this pair is only rewritten after
        // the NEXT pair's first lds_barrier (W phase writes wst, not hst),
        // and every thread reads hst before issuing its next H-phase write,
        // which is separated by that barrier.
    }
    __builtin_amdgcn_s_setprio(0);
    block_reduce_atomic(local, red, &acc[0]);
}

__device__ void mse_block(const float4* __restrict__ a, const float4* __restrict__ b,
                          float* __restrict__ acc, float* red, int mb) {
    float local = 0.f;
    for (int i = mb * 256 + threadIdx.x; i < VOL / 4; i += 512 * 256) {
        const float4 x = a[i], y = b[i];
        const float d0 = x.x - y.x, d1 = x.y - y.y, d2 = x.z - y.z, d3 = x.w - y.w;
        local += d0 * d0 + d1 * d1 + d2 * d2 + d3 * d3;
    }
    block_reduce_atomic(local, red, &acc[1]);
}

__device__ void smooth_block(const float4* __restrict__ s,
                             float* __restrict__ acc, float* red, int sb) {
    float local = 0.f;
    for (int f = sb * 256 + threadIdx.x; f < FLOWN / 4; f += 2048 * 256) {
        const int w4 = f & 31, h = (f >> 5) & 127, d = (f >> 12) & 127;
        const float4 v = s[f];
        const float t1 = v.y - v.x, t2 = v.z - v.y, t3 = v.w - v.z;
        local += t1 * t1 + t2 * t2 + t3 * t3;
        if (w4 < 31) {
            const float nx = ((const float*)s)[4 * f + 4];
            const float t = nx - v.w;
            local += t * t;
        }
        if (h < 127) {
            const float4 nh = s[f + 32];
            const float u0 = nh.x - v.x, u1 = nh.y - v.y, u2 = nh.z - v.z, u3 = nh.w - v.w;
            local += u0 * u0 + u1 * u1 + u2 * u2 + u3 * u3;
        }
        if (d < 127) {
            const float4 nd = s[f + 4096];
            const float u0 = nd.x - v.x, u1 = nd.y - v.y, u2 = nd.z - v.z, u3 = nd.w - v.w;
            local += u0 * u0 + u1 * u1 + u2 * u2 + u3 * u3;
        }
    }
    block_reduce_atomic(local, red, &acc[2]);
}

// 512 ncc blocks FIRST (2/CU); mse (512) / smooth (2048) backfill the
// remaining 4 slots/CU (LDS 26.24KB -> 6 slots) and drain HBM concurrently.
__global__ __launch_bounds__(256) void fused_k(const float* __restrict__ imgsA,
                                               const float* __restrict__ recon,
                                               const float* __restrict__ warped,
                                               const float* __restrict__ flow,
                                               float* __restrict__ acc) {
    __shared__ NccLds Lsh;
    __shared__ float red[4];
    const int g = blockIdx.x;
    if (g < 512) {
        ncc_block(warped, imgsA, acc, &Lsh, red, g);
    } else {
        const int x = g - 512;
        const int q = x / 5, r = x - q * 5;
        if (r == 0) mse_block((const float4*)imgsA, (const float4*)recon, acc, red, q);
        else        smooth_block((const float4*)flow, acc, red, q * 4 + (r - 1));
    }
}

__global__ void fin_k(const float* __restrict__ acc, float* __restrict__ out) {
    if (threadIdx.x == 0) {
        out[0] = 1.0f - acc[0] * (1.0f / (float)VOL);
        out[1] = acc[1] * (1.0f / (float)VOL);
        out[2] = acc[2] * (1.0f / (3.0f * SMCNT));
    }
}

extern "C" void kernel_launch(void* const* d_in, const int* in_sizes, int n_in,
                              void* d_out, int out_size, void* d_ws, size_t ws_size,
                              hipStream_t stream) {
    const float* imgsA  = (const float*)d_in[0];
    const float* recon  = (const float*)d_in[1];
    const float* warped = (const float*)d_in[2];
    const float* flow   = (const float*)d_in[3];
    float* out = (float*)d_out;
    float* acc = (float*)d_ws;

    hipMemsetAsync(d_ws, 0, 16, stream);
    fused_k<<<3072, 256, 0, stream>>>(imgsA, recon, warped, flow, acc);
    fin_k<<<1, 64, 0, stream>>>(acc, out);
}